// Round 1
// baseline (8241.734 us; speedup 1.0000x reference)
//
#include <hip/hip_runtime.h>
#include <hip/hip_bf16.h>
#include <math.h>

// Problem constants (B=1)
#define SEQ    2048
#define HID    4096
#define NHEAD  32
#define HD     128
#define QKVN   12288   // 3*HID

// ---------------- fp32 tiled SGEMM: C[M,N] = A[M,K] @ B[K,N] ----------------
#define BM 128
#define BN 128
#define BK 8
#define TM 8
#define TN 8

__global__ __launch_bounds__(256) void sgemm_kernel(const float* __restrict__ A,
                                                    const float* __restrict__ B,
                                                    float* __restrict__ C,
                                                    int M, int N, int K) {
    __shared__ float As[BK][BM];
    __shared__ float Bs[BK][BN];

    const int tid  = threadIdx.x;
    const int brow = blockIdx.y * BM;
    const int bcol = blockIdx.x * BN;

    const int tr = tid >> 4;          // 0..15 -> row group
    const int tc = tid & 15;          // 0..15 -> col group

    // A-tile load mapping: 128 rows x 8 cols, float4 per thread
    const int arow = tid >> 1;        // 0..127
    const int acol = (tid & 1) * 4;   // 0 or 4
    // B-tile load mapping: 8 rows x 128 cols, float4 per thread
    const int brl = tid >> 5;         // 0..7
    const int bcl = (tid & 31) * 4;   // 0..124

    float acc[TM][TN];
    #pragma unroll
    for (int i = 0; i < TM; ++i)
        #pragma unroll
        for (int j = 0; j < TN; ++j) acc[i][j] = 0.f;

    for (int k0 = 0; k0 < K; k0 += BK) {
        float4 a4 = *(const float4*)&A[(size_t)(brow + arow) * K + k0 + acol];
        As[acol + 0][arow] = a4.x;
        As[acol + 1][arow] = a4.y;
        As[acol + 2][arow] = a4.z;
        As[acol + 3][arow] = a4.w;
        *(float4*)&Bs[brl][bcl] = *(const float4*)&B[(size_t)(k0 + brl) * N + bcol + bcl];
        __syncthreads();

        #pragma unroll
        for (int k = 0; k < BK; ++k) {
            float4 a0 = *(float4*)&As[k][tr * TM];
            float4 a1 = *(float4*)&As[k][tr * TM + 4];
            float4 b0 = *(float4*)&Bs[k][tc * TN];
            float4 b1 = *(float4*)&Bs[k][tc * TN + 4];
            float ar[TM] = {a0.x, a0.y, a0.z, a0.w, a1.x, a1.y, a1.z, a1.w};
            float br[TN] = {b0.x, b0.y, b0.z, b0.w, b1.x, b1.y, b1.z, b1.w};
            #pragma unroll
            for (int i = 0; i < TM; ++i)
                #pragma unroll
                for (int j = 0; j < TN; ++j)
                    acc[i][j] = fmaf(ar[i], br[j], acc[i][j]);
        }
        __syncthreads();
    }

    #pragma unroll
    for (int i = 0; i < TM; ++i) {
        size_t row = (size_t)(brow + tr * TM + i);
        *(float4*)&C[row * N + bcol + tc * TN]     = make_float4(acc[i][0], acc[i][1], acc[i][2], acc[i][3]);
        *(float4*)&C[row * N + bcol + tc * TN + 4] = make_float4(acc[i][4], acc[i][5], acc[i][6], acc[i][7]);
    }
}

// ---------------- RoPE (NeoX style), in-place on q and k slices of qkv ----------------
__global__ __launch_bounds__(256) void rope_kernel(float* __restrict__ qkv,
                                                   const int* __restrict__ pos_ids) {
    int id = blockIdx.x * blockDim.x + threadIdx.x;   // SEQ * NHEAD * 64
    if (id >= SEQ * NHEAD * 64) return;
    const int d = id & 63;
    const int h = (id >> 6) & (NHEAD - 1);
    const int s = id >> 11;

    const float pos = (float)pos_ids[s];
    // inv_freq = 10000^(-d/64)
    const float inv = expf(-9.210340371976184f * ((float)d * (1.0f / 64.0f)));
    const float f = pos * inv;
    float sn, cs;
    sincosf(f, &sn, &cs);

    {   // q
        float* q = qkv + (size_t)s * QKVN + h * HD;
        float x1 = q[d], x2 = q[d + 64];
        q[d]      = x1 * cs - x2 * sn;
        q[d + 64] = x2 * cs + x1 * sn;
    }
    {   // k
        float* k = qkv + (size_t)s * QKVN + HID + h * HD;
        float x1 = k[d], x2 = k[d + 64];
        k[d]      = x1 * cs - x2 * sn;
        k[d + 64] = x2 * cs + x1 * sn;
    }
}

// ---------------- fp32 flash attention (causal), BQ=32 x BKV=64 ----------------
#define FA_BQ  32
#define FA_BKV 64

__global__ __launch_bounds__(256) void flash_attn_kernel(const float* __restrict__ qkv,
                                                         float* __restrict__ attn) {
    __shared__ float Qs[FA_BQ][HD];       // 16 KB
    __shared__ float Ks[FA_BKV][HD];      // 32 KB
    __shared__ float Vs[FA_BKV][HD];      // 32 KB
    __shared__ float Ps[FA_BQ][FA_BKV];   //  8 KB

    const int tid  = threadIdx.x;
    const int qb   = blockIdx.x;          // 0..63
    const int head = blockIdx.y;          // 0..31
    const int q0   = qb * FA_BQ;
    const float scale = 0.08838834764831845f;   // 1/sqrt(128)

    // load Q tile
    for (int i = tid; i < FA_BQ * HD / 4; i += 256) {
        int r = i >> 5;
        int c = (i & 31) * 4;
        *(float4*)&Qs[r][c] = *(const float4*)&qkv[(size_t)(q0 + r) * QKVN + head * HD + c];
    }

    const int qrow  = tid >> 3;     // 0..31
    const int kgrp  = tid & 7;      // 0..7: 8 kv cols each
    const int dbase = (tid & 7) * 16;

    float m = -1e30f, l = 0.f;
    float acc[16];
    #pragma unroll
    for (int i = 0; i < 16; ++i) acc[i] = 0.f;

    const int qg = q0 + qrow;
    const int kv_end = q0 + FA_BQ - 1;   // last needed kv row (causal)

    for (int kv0 = 0; kv0 <= kv_end; kv0 += FA_BKV) {
        __syncthreads();   // previous PV done before K/V overwrite
        for (int i = tid; i < FA_BKV * HD / 4; i += 256) {
            int r = i >> 5;
            int c = (i & 31) * 4;
            *(float4*)&Ks[r][c] = *(const float4*)&qkv[(size_t)(kv0 + r) * QKVN + HID + head * HD + c];
            *(float4*)&Vs[r][c] = *(const float4*)&qkv[(size_t)(kv0 + r) * QKVN + 2 * HID + head * HD + c];
        }
        __syncthreads();

        // scores: this thread covers s[qrow][kgrp*8 + j]
        float sc[8];
        #pragma unroll
        for (int j = 0; j < 8; ++j) sc[j] = 0.f;
        const int kbase = kgrp * 8;
        for (int d = 0; d < HD; d += 4) {
            float4 qv = *(float4*)&Qs[qrow][d];
            #pragma unroll
            for (int j = 0; j < 8; ++j) {
                float4 kv = *(float4*)&Ks[kbase + j][d];
                sc[j] += qv.x * kv.x + qv.y * kv.y + qv.z * kv.z + qv.w * kv.w;
            }
        }
        // causal mask + scale
        #pragma unroll
        for (int j = 0; j < 8; ++j) {
            int kg = kv0 + kbase + j;
            sc[j] = (kg <= qg) ? sc[j] * scale : -1e30f;
        }
        // row max across 8 regs then 8 lanes
        float pm = sc[0];
        #pragma unroll
        for (int j = 1; j < 8; ++j) pm = fmaxf(pm, sc[j]);
        #pragma unroll
        for (int off = 1; off < 8; off <<= 1) pm = fmaxf(pm, __shfl_xor(pm, off));

        float mnew = fmaxf(m, pm);
        float corr = expf(m - mnew);
        float psum = 0.f;
        #pragma unroll
        for (int j = 0; j < 8; ++j) {
            sc[j] = expf(sc[j] - mnew);
            psum += sc[j];
        }
        #pragma unroll
        for (int off = 1; off < 8; off <<= 1) psum += __shfl_xor(psum, off);
        l = l * corr + psum;
        m = mnew;

        #pragma unroll
        for (int j = 0; j < 8; ++j) Ps[qrow][kbase + j] = sc[j];
        __syncthreads();

        // PV: this thread covers O[qrow][dbase .. dbase+15]
        #pragma unroll
        for (int i = 0; i < 16; ++i) acc[i] *= corr;
        for (int j = 0; j < FA_BKV; ++j) {
            float pv = Ps[qrow][j];
            float4 v0 = *(float4*)&Vs[j][dbase];
            float4 v1 = *(float4*)&Vs[j][dbase + 4];
            float4 v2 = *(float4*)&Vs[j][dbase + 8];
            float4 v3 = *(float4*)&Vs[j][dbase + 12];
            acc[0]  = fmaf(pv, v0.x, acc[0]);  acc[1]  = fmaf(pv, v0.y, acc[1]);
            acc[2]  = fmaf(pv, v0.z, acc[2]);  acc[3]  = fmaf(pv, v0.w, acc[3]);
            acc[4]  = fmaf(pv, v1.x, acc[4]);  acc[5]  = fmaf(pv, v1.y, acc[5]);
            acc[6]  = fmaf(pv, v1.z, acc[6]);  acc[7]  = fmaf(pv, v1.w, acc[7]);
            acc[8]  = fmaf(pv, v2.x, acc[8]);  acc[9]  = fmaf(pv, v2.y, acc[9]);
            acc[10] = fmaf(pv, v2.z, acc[10]); acc[11] = fmaf(pv, v2.w, acc[11]);
            acc[12] = fmaf(pv, v3.x, acc[12]); acc[13] = fmaf(pv, v3.y, acc[13]);
            acc[14] = fmaf(pv, v3.z, acc[14]); acc[15] = fmaf(pv, v3.w, acc[15]);
        }
    }

    // epilogue: attn[s][head*HD + d] = acc / l
    const float inv_l = 1.0f / l;
    float* outp = attn + (size_t)qg * HID + head * HD + dbase;
    #pragma unroll
    for (int i = 0; i < 16; i += 4) {
        *(float4*)&outp[i] = make_float4(acc[i] * inv_l, acc[i + 1] * inv_l,
                                         acc[i + 2] * inv_l, acc[i + 3] * inv_l);
    }
}

extern "C" void kernel_launch(void* const* d_in, const int* in_sizes, int n_in,
                              void* d_out, int out_size, void* d_ws, size_t ws_size,
                              hipStream_t stream) {
    const float* hidden  = (const float*)d_in[0];
    const int*   pos_ids = (const int*)d_in[1];
    const float* W_qkv   = (const float*)d_in[2];
    const float* W_o     = (const float*)d_in[3];
    float*       out     = (float*)d_out;

    float* qkv  = (float*)d_ws;                                   // SEQ*QKVN f32 = 100.7 MB
    float* attn = (float*)((char*)d_ws + (size_t)SEQ * QKVN * 4); // SEQ*HID  f32 = 33.6 MB

    // 1) qkv = hidden @ W_qkv   (2048 x 4096 @ 4096 x 12288)
    {
        dim3 grid(QKVN / BN, SEQ / BM);
        sgemm_kernel<<<grid, 256, 0, stream>>>(hidden, W_qkv, qkv, SEQ, QKVN, HID);
    }
    // 2) RoPE in place on q,k
    {
        int total = SEQ * NHEAD * 64;
        rope_kernel<<<(total + 255) / 256, 256, 0, stream>>>(qkv, pos_ids);
    }
    // 3) causal flash attention -> attn
    {
        dim3 grid(SEQ / FA_BQ, NHEAD);
        flash_attn_kernel<<<grid, 256, 0, stream>>>(qkv, attn);
    }
    // 4) out = attn @ W_o   (2048 x 4096 @ 4096 x 4096)
    {
        dim3 grid(HID / BN, SEQ / BM);
        sgemm_kernel<<<grid, 256, 0, stream>>>(attn, W_o, out, SEQ, HID, HID);
    }
}

// Round 2
// 619.583 us; speedup vs baseline: 13.3021x; 13.3021x over previous
//
#include <hip/hip_runtime.h>
#include <hip/hip_bf16.h>
#include <math.h>

#define SEQ   2048
#define HID   4096
#define NHEAD 32
#define HD    128
#define QKVN  12288

typedef __bf16 bf16;
typedef __bf16 bf16x8 __attribute__((ext_vector_type(8)));
typedef __bf16 bf16x4 __attribute__((ext_vector_type(4)));
typedef float  f32x4  __attribute__((ext_vector_type(4)));

#define AS1 __attribute__((address_space(1)))
#define AS3 __attribute__((address_space(3)))

__device__ __forceinline__ void gload16(const void* g, void* l) {
    __builtin_amdgcn_global_load_lds((const AS1 void*)g, (AS3 void*)l, 16, 0, 0);
}

__device__ __forceinline__ unsigned short bbits(bf16 b) {
    union { bf16 b; unsigned short u; } x; x.b = b; return x.u;
}

// ---------------- bf16 MFMA GEMM: C[M,N] = A[M,K] @ Bt[N,K]^T ----------------
// m97-style: 128x128 tile, BK=32, 4 waves (each 64x64), global_load_lds staging.
// OB==0: C f32; OB==1: C bf16.
template<int OB>
__global__ __launch_bounds__(256) void gemm_bt(const bf16* __restrict__ A,
                                               const bf16* __restrict__ Bt,
                                               void* __restrict__ Cv,
                                               int M, int N, int K) {
    __shared__ __attribute__((aligned(16))) char As[128 * 32 * 2];
    __shared__ __attribute__((aligned(16))) char Bs[128 * 32 * 2];
    const int tid  = threadIdx.x;
    const int l    = tid & 63;
    const int wave = tid >> 6;
    const int wr   = wave >> 1, wc = wave & 1;
    const int brow = blockIdx.y * 128, bcol = blockIdx.x * 128;

    f32x4 acc[4][4];
    #pragma unroll
    for (int i = 0; i < 4; ++i)
        #pragma unroll
        for (int j = 0; j < 4; ++j) acc[i][j] = (f32x4){0.f, 0.f, 0.f, 0.f};

    const char* Ab = (const char*)A;
    const char* Bb = (const char*)Bt;
    const size_t rowb = (size_t)K * 2;

    for (int k0 = 0; k0 < K; k0 += 32) {
        __syncthreads();
        // stage A,B tiles: [128 rows][32 k] bf16 = 8KB each; rows 64B = 4 slots of 16B.
        // source-swizzled so LDS slot s holds row bytes (s*16)^((r&3)<<4).
        #pragma unroll
        for (int i = 0; i < 2; ++i) {
            int c  = i * 256 + tid;
            int r  = c >> 2, sl = c & 3;
            int so = (sl * 16) ^ ((r & 3) << 4);
            gload16(Ab + (size_t)(brow + r) * rowb + (size_t)k0 * 2 + so,
                    As + (size_t)(i * 256 + (tid & 192)) * 16);
            gload16(Bb + (size_t)(bcol + r) * rowb + (size_t)k0 * 2 + so,
                    Bs + (size_t)(i * 256 + (tid & 192)) * 16);
        }
        __syncthreads();

        bf16x8 af[4], bfr[4];
        #pragma unroll
        for (int mf = 0; mf < 4; ++mf) {
            int r = wr * 64 + mf * 16 + (l & 15);
            af[mf] = *(const bf16x8*)(As + r * 64 + (((l >> 4) * 16) ^ ((r & 3) << 4)));
        }
        #pragma unroll
        for (int nf = 0; nf < 4; ++nf) {
            int r = wc * 64 + nf * 16 + (l & 15);
            bfr[nf] = *(const bf16x8*)(Bs + r * 64 + (((l >> 4) * 16) ^ ((r & 3) << 4)));
        }
        #pragma unroll
        for (int mf = 0; mf < 4; ++mf)
            #pragma unroll
            for (int nf = 0; nf < 4; ++nf)
                acc[mf][nf] = __builtin_amdgcn_mfma_f32_16x16x32_bf16(af[mf], bfr[nf], acc[mf][nf], 0, 0, 0);
    }

    // C/D layout: col = l&15, row = (l>>4)*4 + j
    #pragma unroll
    for (int mf = 0; mf < 4; ++mf) {
        #pragma unroll
        for (int j = 0; j < 4; ++j) {
            int row = brow + wr * 64 + mf * 16 + (l >> 4) * 4 + j;
            #pragma unroll
            for (int nf = 0; nf < 4; ++nf) {
                int col = bcol + wc * 64 + nf * 16 + (l & 15);
                if (OB == 0) ((float*)Cv)[(size_t)row * N + col] = acc[mf][nf][j];
                else         ((bf16*)Cv)[(size_t)row * N + col] = (bf16)acc[mf][nf][j];
            }
        }
    }
}

// ---------------- f32 -> bf16 flat cast ----------------
__global__ __launch_bounds__(256) void cast_flat(const float* __restrict__ in,
                                                 bf16* __restrict__ out, int n4) {
    int i = blockIdx.x * 256 + threadIdx.x;
    if (i >= n4) return;
    float4 v = ((const float4*)in)[i];
    bf16x4 o = {(bf16)v.x, (bf16)v.y, (bf16)v.z, (bf16)v.w};
    *(bf16x4*)(out + (size_t)i * 4) = o;
}

// ---------------- f32 [R][C] -> bf16 [C][R] transpose-cast ----------------
__global__ __launch_bounds__(256) void cast_transpose(const float* __restrict__ in,
                                                      bf16* __restrict__ out, int R, int C) {
    __shared__ float t[64][65];
    const int r0 = blockIdx.y * 64, c0 = blockIdx.x * 64;
    #pragma unroll
    for (int i = 0; i < 16; ++i) {
        int idx = i * 256 + threadIdx.x;
        int rr = idx >> 6, cc = idx & 63;
        t[rr][cc] = in[(size_t)(r0 + rr) * C + c0 + cc];
    }
    __syncthreads();
    #pragma unroll
    for (int i = 0; i < 16; ++i) {
        int idx = i * 256 + threadIdx.x;
        int rr = idx >> 6, cc = idx & 63;
        out[(size_t)(c0 + rr) * R + r0 + cc] = (bf16)t[cc][rr];
    }
}

// ---------------- RoPE (NeoX) + repack q,k: qkv bf16 -> Qb,Kb [head][seq][hd] ----------------
__global__ __launch_bounds__(256) void rope_repack(const bf16* __restrict__ qkv,
                                                   const int* __restrict__ pos_ids,
                                                   bf16* __restrict__ Qb,
                                                   bf16* __restrict__ Kb) {
    int id = blockIdx.x * 256 + threadIdx.x;   // SEQ*NHEAD*64
    const int d = id & 63;
    const int h = (id >> 6) & (NHEAD - 1);
    const int s = id >> 11;

    const float pos = (float)pos_ids[s];
    const float inv = expf(-9.210340371976184f * ((float)d * (1.0f / 64.0f)));
    float sn, cs;
    sincosf(pos * inv, &sn, &cs);

    const bf16* row = qkv + (size_t)s * QKVN;
    {
        float x1 = (float)row[h * HD + d], x2 = (float)row[h * HD + d + 64];
        bf16* qo = Qb + ((size_t)h * SEQ + s) * HD;
        qo[d]      = (bf16)(x1 * cs - x2 * sn);
        qo[d + 64] = (bf16)(x2 * cs + x1 * sn);
    }
    {
        float x1 = (float)row[HID + h * HD + d], x2 = (float)row[HID + h * HD + d + 64];
        bf16* ko = Kb + ((size_t)h * SEQ + s) * HD;
        ko[d]      = (bf16)(x1 * cs - x2 * sn);
        ko[d + 64] = (bf16)(x2 * cs + x1 * sn);
    }
}

// ---------------- V transpose: qkv bf16 v-slice -> Vt [head][hd][seq] ----------------
__global__ __launch_bounds__(256) void v_transpose(const bf16* __restrict__ qkv,
                                                   bf16* __restrict__ Vt) {
    __shared__ bf16 t[64][130];
    const int h = blockIdx.y, s0 = blockIdx.x * 64;
    #pragma unroll
    for (int i = 0; i < 32; ++i) {
        int idx = i * 256 + threadIdx.x;
        int ss = idx >> 7, dd = idx & 127;
        t[ss][dd] = qkv[(size_t)(s0 + ss) * QKVN + 2 * HID + h * HD + dd];
    }
    __syncthreads();
    #pragma unroll
    for (int i = 0; i < 32; ++i) {
        int idx = i * 256 + threadIdx.x;
        int dd = idx >> 6, ss = idx & 63;
        Vt[((size_t)h * HD + dd) * SEQ + s0 + ss] = t[ss][dd];
    }
}

// ---------------- bf16 MFMA causal flash attention ----------------
// Block: 64 q-rows x 1 head; 4 waves, each owns 16 q-rows. KV tiles of 64.
// S^T = K @ Q^T (swapped operands -> lane-local softmax row), P via swizzled LDS,
// PV from transposed-V LDS tile.
__global__ __launch_bounds__(256) void attn_mfma(const bf16* __restrict__ Qb,
                                                 const bf16* __restrict__ Kb,
                                                 const bf16* __restrict__ Vt,
                                                 bf16* __restrict__ attn) {
    __shared__ __attribute__((aligned(16))) char Ks[64 * 256];    // [kv][d] 16KB, 256B rows
    __shared__ __attribute__((aligned(16))) char Vs[128 * 128];   // [d][kv] 16KB, 128B rows
    __shared__ __attribute__((aligned(16))) char Ps[4 * 16 * 128]; // per-wave [16 q][64 kv] 8KB
    const int tid  = threadIdx.x, l = tid & 63, wave = tid >> 6;
    const int head = blockIdx.y;
    const int qb   = gridDim.x - 1 - blockIdx.x;   // heavy blocks first
    const int q0   = qb * 64;
    const int qw   = q0 + wave * 16;
    const float scale = 0.08838834764831845f;      // 1/sqrt(128)

    // Q fragments in registers: lane reads Q[qw + (l&15)][kc*32 + (l>>4)*8 ..+8]
    bf16x8 qf[4];
    const bf16* Qg = Qb + ((size_t)head * SEQ + qw + (l & 15)) * HD;
    #pragma unroll
    for (int kc = 0; kc < 4; ++kc) qf[kc] = *(const bf16x8*)(Qg + kc * 32 + (l >> 4) * 8);

    f32x4 o[8];
    #pragma unroll
    for (int i = 0; i < 8; ++i) o[i] = (f32x4){0.f, 0.f, 0.f, 0.f};
    float mrun = -1e30f, lrun = 0.f;
    const int qrow  = qw + (l & 15);    // softmax row owned by this lane
    const int ntile = qb + 1;

    const char* Kg = (const char*)(Kb + (size_t)head * SEQ * HD);
    const char* Vg = (const char*)(Vt + (size_t)head * HD * SEQ);
    char* Pw = Ps + wave * 2048;

    for (int t = 0; t < ntile; ++t) {
        const int kv0 = t * 64;
        __syncthreads();
        // stage K [64][256B] (16-slot swz) and Vt [128][128B] (8-slot swz)
        #pragma unroll
        for (int i = 0; i < 4; ++i) {
            int c = i * 256 + tid;
            {
                int r = c >> 4, sl = c & 15;
                int so = (sl * 16) ^ ((r & 15) << 4);
                gload16(Kg + (size_t)(kv0 + r) * 256 + so,
                        Ks + (size_t)(i * 256 + (tid & 192)) * 16);
            }
            {
                int r = c >> 3, sl = c & 7;
                int so = (sl * 16) ^ ((r & 7) << 4);
                gload16(Vg + (size_t)r * (SEQ * 2) + (size_t)kv0 * 2 + so,
                        Vs + (size_t)(i * 256 + (tid & 192)) * 16);
            }
        }
        __syncthreads();

        // S^T[kv][q] = K @ Q^T : A-frag rows = kv, B-frag = Q regs
        f32x4 st[4];
        #pragma unroll
        for (int mf = 0; mf < 4; ++mf) {
            f32x4 s = (f32x4){0.f, 0.f, 0.f, 0.f};
            #pragma unroll
            for (int kc = 0; kc < 4; ++kc) {
                int rk = mf * 16 + (l & 15);
                bf16x8 a = *(const bf16x8*)(Ks + rk * 256 +
                              ((kc * 64 + (l >> 4) * 16) ^ ((rk & 15) << 4)));
                s = __builtin_amdgcn_mfma_f32_16x16x32_bf16(a, qf[kc], s, 0, 0, 0);
            }
            st[mf] = s;
        }

        // online softmax: lane holds S[qrow][kv] for kv = kv0 + mf*16 + (l>>4)*4 + j
        float pm = -1e30f;
        #pragma unroll
        for (int mf = 0; mf < 4; ++mf)
            #pragma unroll
            for (int j = 0; j < 4; ++j) {
                int kv = kv0 + mf * 16 + (l >> 4) * 4 + j;
                float v = (kv <= qrow) ? st[mf][j] * scale : -1e30f;
                st[mf][j] = v;
                pm = fmaxf(pm, v);
            }
        pm = fmaxf(pm, __shfl_xor(pm, 16));
        pm = fmaxf(pm, __shfl_xor(pm, 32));
        float mn   = fmaxf(mrun, pm);
        float corr = __expf(mrun - mn);
        float ls = 0.f;
        #pragma unroll
        for (int mf = 0; mf < 4; ++mf)
            #pragma unroll
            for (int j = 0; j < 4; ++j) {
                float p = __expf(st[mf][j] - mn);
                st[mf][j] = p;
                ls += p;
            }
        ls += __shfl_xor(ls, 16);
        ls += __shfl_xor(ls, 32);
        lrun = lrun * corr + ls;
        mrun = mn;

        // rescale O: acc rows are q16=(l>>4)*4+r, corr held by lane q16
        f32x4 cv;
        #pragma unroll
        for (int r = 0; r < 4; ++r) cv[r] = __shfl(corr, (l >> 4) * 4 + r, 64);
        #pragma unroll
        for (int nf = 0; nf < 8; ++nf) o[nf] *= cv;

        // write P as bf16 into swizzled LDS [16 q][64 kv] (pairs -> b32)
        #pragma unroll
        for (int mf = 0; mf < 4; ++mf)
            #pragma unroll
            for (int r = 0; r < 4; r += 2) {
                int kv = mf * 16 + (l >> 4) * 4 + r;
                unsigned pk = (unsigned)bbits((bf16)st[mf][r]) |
                              ((unsigned)bbits((bf16)st[mf][r + 1]) << 16);
                *(unsigned*)(Pw + (l & 15) * 128 + ((kv * 2) ^ ((l & 15 & 7) << 4))) = pk;
            }

        // PV: O[q][d] += P[q][kv] V[kv][d]
        #pragma unroll
        for (int kc = 0; kc < 2; ++kc) {
            bf16x8 pa = *(const bf16x8*)(Pw + (l & 15) * 128 +
                           ((kc * 64 + (l >> 4) * 16) ^ ((l & 7) << 4)));
            #pragma unroll
            for (int nf = 0; nf < 8; ++nf) {
                int dr = nf * 16 + (l & 15);
                bf16x8 vb = *(const bf16x8*)(Vs + dr * 128 +
                               ((kc * 64 + (l >> 4) * 16) ^ ((dr & 7) << 4)));
                o[nf] = __builtin_amdgcn_mfma_f32_16x16x32_bf16(pa, vb, o[nf], 0, 0, 0);
            }
        }
    }

    // epilogue: attn[s][head*128 + d] = O/l  (bf16)
    float il = 1.0f / lrun;
    f32x4 iv;
    #pragma unroll
    for (int r = 0; r < 4; ++r) iv[r] = __shfl(il, (l >> 4) * 4 + r, 64);
    #pragma unroll
    for (int nf = 0; nf < 8; ++nf)
        #pragma unroll
        for (int r = 0; r < 4; ++r) {
            int row = qw + (l >> 4) * 4 + r;
            attn[(size_t)row * HID + head * HD + nf * 16 + (l & 15)] = (bf16)(o[nf][r] * iv[r]);
        }
}

extern "C" void kernel_launch(void* const* d_in, const int* in_sizes, int n_in,
                              void* d_out, int out_size, void* d_ws, size_t ws_size,
                              hipStream_t stream) {
    const float* hidden  = (const float*)d_in[0];
    const int*   pos_ids = (const int*)d_in[1];
    const float* W_qkv   = (const float*)d_in[2];
    const float* W_o     = (const float*)d_in[3];
    float*       out     = (float*)d_out;
    char*        ws      = (char*)d_ws;

    // phase-1 layout
    bf16* Wqkv_t   = (bf16*)(ws);                    // [12288][4096] bf16 = 100663296 B
    bf16* qkv_b    = (bf16*)(ws + 100663296);        // [2048][12288] bf16 =  50331648 B
    bf16* hidden_b = (bf16*)(ws + 150994944);        // [2048][4096]  bf16 =  16777216 B
    // phase-2 layout (aliases Wqkv_t region, used only after GEMM1 completes)
    bf16* Qb     = (bf16*)(ws);                      // [32][2048][128]
    bf16* Kb     = (bf16*)(ws + 16777216);
    bf16* Vtb    = (bf16*)(ws + 33554432);           // [32][128][2048]
    bf16* attn_b = (bf16*)(ws + 50331648);           // [2048][4096]
    bf16* Wo_t   = (bf16*)(ws + 67108864);           // [4096][4096]

    // 1) casts
    cast_flat<<<(SEQ * HID / 4 + 255) / 256, 256, 0, stream>>>(hidden, hidden_b, SEQ * HID / 4);
    cast_transpose<<<dim3(QKVN / 64, HID / 64), 256, 0, stream>>>(W_qkv, Wqkv_t, HID, QKVN);
    // 2) qkv = hidden @ W_qkv  (bf16 out)
    gemm_bt<1><<<dim3(QKVN / 128, SEQ / 128), 256, 0, stream>>>(hidden_b, Wqkv_t, qkv_b, SEQ, QKVN, HID);
    // 3) RoPE + repack to [head][seq][hd]; V transposed to [head][hd][seq]
    rope_repack<<<(SEQ * NHEAD * 64) / 256, 256, 0, stream>>>(qkv_b, pos_ids, Qb, Kb);
    v_transpose<<<dim3(SEQ / 64, NHEAD), 256, 0, stream>>>(qkv_b, Vtb);
    // 4) W_o transpose-cast (after GEMM1: region aliases Wqkv_t)
    cast_transpose<<<dim3(HID / 64, HID / 64), 256, 0, stream>>>(W_o, Wo_t, HID, HID);
    // 5) attention
    attn_mfma<<<dim3(SEQ / 64, NHEAD), 256, 0, stream>>>(Qb, Kb, Vtb, attn_b);
    // 6) out = attn @ W_o  (f32 out)
    gemm_bt<0><<<dim3(HID / 128, SEQ / 128), 256, 0, stream>>>(attn_b, Wo_t, out, SEQ, HID, HID);
}